// Round 1
// baseline (520.829 us; speedup 1.0000x reference)
//
#include <hip/hip_runtime.h>
#include <hip/hip_bf16.h>

// Linear4bit: out[M,OUT] = dq(x)·dq(W)^T + dq(x[:, :128])·dq(W_lr)^T
// M=8192, IN=4096, OUT=4096, R=128. All inputs int32 (one byte value / elem).
// Strategy R1: fused-dequant f16 MFMA GEMM, 128x128x64 tiles, K extended to 4224.

#define M_DIM 8192
#define N_DIM 4096
#define K_MAIN 4096
#define K_TOT 4224
#define BM 128
#define BN 128
#define BK 64

typedef __attribute__((ext_vector_type(4))) float f32x4;
typedef __attribute__((ext_vector_type(8))) short short8;
typedef __attribute__((ext_vector_type(8))) _Float16 half8;
typedef __attribute__((ext_vector_type(4))) int i32x4;

// Decode 4 packed bytes (given as 4 int32s, values 0..255) + one E8M0 scale
// into 8 dequantized f16 values (bit pattern in short8).
// Element order produced: [e0,e2,e4,e6, e1,e3,e5,e7] (k-permuted; A and B use
// the same permutation within a 32-block so the dot product is unchanged).
__device__ inline short8 dequant8_f16(i32x4 q, int sf) {
    unsigned b = (unsigned)q.x | ((unsigned)q.y << 8) |
                 ((unsigned)q.z << 16) | ((unsigned)q.w << 24);
    unsigned me = b & 0x07070707u;         // magnitudes of even elements (low nibbles)
    unsigned mo = (b >> 4) & 0x07070707u;  // magnitudes of odd elements (high nibbles)
    // f16 high bytes for fp4 magnitudes 0..7: 0x00,0x38,0x3C,0x3E,0x40,0x42,0x44,0x46
    const unsigned TLO = 0x3E3C3800u;  // sel 0..3  (v_perm S1)
    const unsigned THI = 0x46444240u;  // sel 4..7  (v_perm S0)
    unsigned He = __builtin_amdgcn_perm(THI, TLO, me);
    unsigned Ho = __builtin_amdgcn_perm(THI, TLO, mo);
    He |= (b & 0x08080808u) << 4;  // even signs -> byte MSB
    Ho |= (b & 0x80808080u);       // odd signs already at byte MSB
    // zip high bytes with zero low bytes -> f16 lanes
    unsigned d0 = __builtin_amdgcn_perm(He, 0u, 0x05010400u);  // [0,He0,0,He1] = (e0,e2)
    unsigned d1 = __builtin_amdgcn_perm(He, 0u, 0x07000600u);  // (e4,e6)
    unsigned d2 = __builtin_amdgcn_perm(Ho, 0u, 0x05010400u);  // (e1,e3)
    unsigned d3 = __builtin_amdgcn_perm(Ho, 0u, 0x07000600u);  // (e5,e7)
    i32x4 di;
    di.x = (int)d0; di.y = (int)d1; di.z = (int)d2; di.w = (int)d3;
    half8 h = __builtin_bit_cast(half8, di);
    // scale = 2^(sf-127), exact in f16 for sf in [120,134)
    unsigned short se = (unsigned short)((sf - 112) << 10);
    int srep = (int)((unsigned)se | ((unsigned)se << 16));
    i32x4 si;
    si.x = srep; si.y = srep; si.z = srep; si.w = srep;
    half8 hs = __builtin_bit_cast(half8, si);
    h = h * hs;  // v_pk_mul_f16, exact (power-of-2 scale, no denorm/overflow)
    return __builtin_bit_cast(short8, h);
}

__global__ __launch_bounds__(256)
void l4b_kernel(const int* __restrict__ x_q, const int* __restrict__ scales_x,
                const int* __restrict__ weight, const int* __restrict__ SF_w,
                const int* __restrict__ lrw, const int* __restrict__ SF_lr,
                float* __restrict__ out) {
    // LDS tiles, f16 bits, [row][k] with XOR swizzle: byte ^= (row&7)<<4
    __shared__ short As[BM * BK];
    __shared__ short Bs[BN * BK];

    const int tid = threadIdx.x;
    const int lane = tid & 63;
    const int wid = tid >> 6;
    const int wr = wid >> 1;  // 0..1
    const int wc = wid & 1;   // 0..1

    const int bm = blockIdx.y * BM;
    const int bn = blockIdx.x * BN;

    const int srow = tid >> 3;        // 0..31 (+32 per staging iter)
    const int scol = (tid & 7) * 8;   // element column 0,8,...,56

    f32x4 acc[4][4] = {};

    for (int kt = 0; kt < K_TOT / BK; ++kt) {
        const int k0 = kt * BK;
        __syncthreads();  // previous compute must finish before overwriting LDS

        // ---- stage A (x) ----
#pragma unroll
        for (int it = 0; it < 4; ++it) {
            const int row = it * 32 + srow;
            const int gm = bm + row;
            const int k = k0 + scol;
            const int ksrc = (k < K_MAIN) ? k : (k - K_MAIN);  // low-rank replays x[:, :128]
            i32x4 q = *(const i32x4*)(x_q + (size_t)gm * (K_MAIN / 2) + (ksrc >> 1));
            int sf = scales_x[(size_t)gm * (K_MAIN / 32) + (ksrc >> 5)];
            short8 v = dequant8_f16(q, sf);
            unsigned a = (unsigned)(row * (BK * 2) + scol * 2);
            a ^= (unsigned)((row & 7) << 4);
            *(short8*)((char*)As + a) = v;
        }
        // ---- stage B (W or W_lr) ----
#pragma unroll
        for (int it = 0; it < 4; ++it) {
            const int row = it * 32 + srow;
            const int gn = bn + row;
            const int k = k0 + scol;
            i32x4 q;
            int sf;
            if (k < K_MAIN) {
                q = *(const i32x4*)(weight + (size_t)gn * (K_MAIN / 2) + (k >> 1));
                sf = SF_w[(size_t)gn * (K_MAIN / 32) + (k >> 5)];
            } else {
                const int kl = k - K_MAIN;
                q = *(const i32x4*)(lrw + (size_t)gn * 64 + (kl >> 1));
                sf = SF_lr[(size_t)gn * 4 + (kl >> 5)];
            }
            short8 v = dequant8_f16(q, sf);
            unsigned a = (unsigned)(row * (BK * 2) + scol * 2);
            a ^= (unsigned)((row & 7) << 4);
            *(short8*)((char*)Bs + a) = v;
        }
        __syncthreads();

        // ---- compute: 2 K-slices of 32, 4x4 fragments of 16x16 per wave ----
#pragma unroll
        for (int ks = 0; ks < 2; ++ks) {
            const int koff = ks * 32 + (lane >> 4) * 8;
            short8 af[4], bfr[4];
#pragma unroll
            for (int mi = 0; mi < 4; ++mi) {
                const int row = wr * 64 + mi * 16 + (lane & 15);
                unsigned a = (unsigned)(row * (BK * 2) + koff * 2) ^ (unsigned)((row & 7) << 4);
                af[mi] = *(const short8*)((const char*)As + a);
            }
#pragma unroll
            for (int ni = 0; ni < 4; ++ni) {
                const int row = wc * 64 + ni * 16 + (lane & 15);
                unsigned a = (unsigned)(row * (BK * 2) + koff * 2) ^ (unsigned)((row & 7) << 4);
                bfr[ni] = *(const short8*)((const char*)Bs + a);
            }
#pragma unroll
            for (int mi = 0; mi < 4; ++mi)
#pragma unroll
                for (int ni = 0; ni < 4; ++ni)
                    acc[mi][ni] = __builtin_amdgcn_mfma_f32_16x16x32_f16(
                        __builtin_bit_cast(half8, af[mi]),
                        __builtin_bit_cast(half8, bfr[ni]),
                        acc[mi][ni], 0, 0, 0);
        }
    }

    // ---- epilogue: C/D layout col=lane&15, row=(lane>>4)*4+reg (m89/m91) ----
#pragma unroll
    for (int mi = 0; mi < 4; ++mi) {
#pragma unroll
        for (int ni = 0; ni < 4; ++ni) {
            const int col = bn + wc * 64 + ni * 16 + (lane & 15);
            const int row0 = bm + wr * 64 + mi * 16 + (lane >> 4) * 4;
#pragma unroll
            for (int r = 0; r < 4; ++r) {
                out[(size_t)(row0 + r) * N_DIM + col] = acc[mi][ni][r];
            }
        }
    }
}

extern "C" void kernel_launch(void* const* d_in, const int* in_sizes, int n_in,
                              void* d_out, int out_size, void* d_ws, size_t ws_size,
                              hipStream_t stream) {
    const int* x_q   = (const int*)d_in[0];
    const int* sx    = (const int*)d_in[1];
    const int* w     = (const int*)d_in[2];
    const int* sfw   = (const int*)d_in[3];
    const int* lrw   = (const int*)d_in[4];
    const int* sflr  = (const int*)d_in[5];
    float* out = (float*)d_out;

    dim3 grid(N_DIM / BN, M_DIM / BM);
    l4b_kernel<<<grid, dim3(256), 0, stream>>>(x_q, sx, w, sfw, lrw, sflr, out);
}

// Round 2
// 152.739 us; speedup vs baseline: 3.4099x; 3.4099x over previous
//
#include <hip/hip_runtime.h>
#include <hip/hip_bf16.h>
#include <stdint.h>

// Linear4bit: out[M,OUT] = dq(x)·dq(W)^T + dq(x[:, :128])·dq(W_lr)^T
// R2 strategy: (1) pack_kernel compresses int32-per-byte inputs into true
// packed-fp4 bytes + transposed scale planes in d_ws, with K extended to
// 4224 (low-rank appended). (2) GEMM uses mfma_scale_f32_32x32x64_f8f6f4
// (HW dequant). Fallback to R1 fused-f16 kernel if ws too small.

#define M_DIM 8192
#define N_DIM 4096
#define K_MAIN 4096
#define K_TOT 4224
#define KB_TOT 2112   // packed bytes per extended row
#define NBLK 132      // scale blocks per extended row

// ---- ws layout ----
#define XE_OFF   ((size_t)0)
#define WE_OFF   (XE_OFF + (size_t)M_DIM * KB_TOT)     // 17,301,504
#define SXT_OFF  (WE_OFF + (size_t)N_DIM * KB_TOT)     // 25,952,256
#define SWT_OFF  (SXT_OFF + (size_t)NBLK * M_DIM)      // 27,033,600
#define WS_NEED  (SWT_OFF + (size_t)NBLK * N_DIM)      // 27,574,272

typedef __attribute__((ext_vector_type(4))) float f32x4;
typedef __attribute__((ext_vector_type(16))) float f32x16;
typedef __attribute__((ext_vector_type(8))) short short8;
typedef __attribute__((ext_vector_type(8))) _Float16 half8;
typedef __attribute__((ext_vector_type(4))) int i32x4;
typedef __attribute__((ext_vector_type(8))) int i32x8;

// ======================= pack / transpose pre-pass =======================
#define PX_N  (M_DIM * (KB_TOT / 4))            // 4,325,376
#define PW_N  (N_DIM * (KB_TOT / 4))            // 2,162,688
#define TSX_N (NBLK * (M_DIM / 4))              // 270,336
#define TSW_N (NBLK * (N_DIM / 4))              // 135,168
#define PACK_TOTAL (PX_N + PW_N + TSX_N + TSW_N)  // 6,893,568

__global__ __launch_bounds__(256)
void pack_kernel(const int* __restrict__ xq, const int* __restrict__ sx,
                 const int* __restrict__ w, const int* __restrict__ sfw,
                 const int* __restrict__ lrw, const int* __restrict__ sflr,
                 uint8_t* __restrict__ ws) {
    int t = blockIdx.x * 256 + threadIdx.x;
    if (t < PX_N) {
        // pack x_ext: byte j of row = (uint8)x_q[row][j'] ; j>=2048 replays j-2048
        int row = t / (KB_TOT / 4);
        int j = (t % (KB_TOT / 4)) * 4;
        int jsrc = (j < 2048) ? j : (j - 2048);
        i32x4 q = *(const i32x4*)(xq + (size_t)row * 2048 + jsrc);
        unsigned v = (q.x & 255) | ((q.y & 255) << 8) | ((q.z & 255) << 16) |
                     ((unsigned)(q.w & 255) << 24);
        *(unsigned*)(ws + XE_OFF + (size_t)row * KB_TOT + j) = v;
    } else if (t < PX_N + PW_N) {
        int i = t - PX_N;
        int row = i / (KB_TOT / 4);
        int j = (i % (KB_TOT / 4)) * 4;
        i32x4 q;
        if (j < 2048) q = *(const i32x4*)(w + (size_t)row * 2048 + j);
        else          q = *(const i32x4*)(lrw + (size_t)row * 64 + (j - 2048));
        unsigned v = (q.x & 255) | ((q.y & 255) << 8) | ((q.z & 255) << 16) |
                     ((unsigned)(q.w & 255) << 24);
        *(unsigned*)(ws + WE_OFF + (size_t)row * KB_TOT + j) = v;
    } else if (t < PX_N + PW_N + TSX_N) {
        // sxT[blk][row]: transposed scale plane for x
        int i = t - PX_N - PW_N;
        int blk = i / (M_DIM / 4);
        int r4 = (i % (M_DIM / 4)) * 4;
        int sblk = (blk < 128) ? blk : (blk - 128);
        unsigned v = 0;
#pragma unroll
        for (int ii = 0; ii < 4; ++ii)
            v |= (unsigned)(sx[(size_t)(r4 + ii) * 128 + sblk] & 255) << (8 * ii);
        *(unsigned*)(ws + SXT_OFF + (size_t)blk * M_DIM + r4) = v;
    } else if (t < PACK_TOTAL) {
        // swT[blk][row]: transposed scale plane for W (blk>=128 -> SF_lr)
        int i = t - PX_N - PW_N - TSX_N;
        int blk = i / (N_DIM / 4);
        int r4 = (i % (N_DIM / 4)) * 4;
        unsigned v = 0;
        if (blk < 128) {
#pragma unroll
            for (int ii = 0; ii < 4; ++ii)
                v |= (unsigned)(sfw[(size_t)(r4 + ii) * 128 + blk] & 255) << (8 * ii);
        } else {
#pragma unroll
            for (int ii = 0; ii < 4; ++ii)
                v |= (unsigned)(sflr[(size_t)(r4 + ii) * 4 + (blk - 128)] & 255) << (8 * ii);
        }
        *(unsigned*)(ws + SWT_OFF + (size_t)blk * N_DIM + r4) = v;
    }
}

// ======================= MX-fp4 GEMM =======================
// Tiles: BM=BN=128, BK=128 elements (64 bytes). 4 waves (2x2), each 64x64 out.
// LDS data k-chunk-major: As[c][row][16B], chunk c covers k-bytes [c*16,c*16+16).
// Fragment: lane l -> row l&31, k-half h=l>>5; MFMA kk uses chunk kk*2+h.

__device__ inline void gload_lds16(const void* g, void* l) {
    __builtin_amdgcn_global_load_lds(
        (const __attribute__((address_space(1))) unsigned int*)g,
        (__attribute__((address_space(3))) unsigned int*)l, 16, 0, 0);
}

__global__ __launch_bounds__(256)
void l4b_mx(const uint8_t* __restrict__ xe, const uint8_t* __restrict__ we,
            const uint8_t* __restrict__ sxT, const uint8_t* __restrict__ swT,
            float* __restrict__ out) {
    __shared__ __align__(16) uint8_t As[4][128][16];
    __shared__ __align__(16) uint8_t Bs[4][128][16];
    __shared__ __align__(16) uint8_t Sa[4][128];
    __shared__ __align__(16) uint8_t Sb[4][128];

    const int tid = threadIdx.x;
    const int lane = tid & 63;
    const int wid = tid >> 6;
    const int wr = wid >> 1;
    const int wc = wid & 1;

    const int wg = blockIdx.x;
    const int bn = (wg & 31) * 128;   // N/128 = 32
    const int bm = (wg >> 5) * 128;

    f32x16 acc[2][2] = {};

    for (int kt = 0; kt < K_TOT / 128; ++kt) {
        __syncthreads();  // previous compute done before overwrite

        // ---- stage A and B: 8 wave-ops each, 2 per wave ----
#pragma unroll
        for (int i = 0; i < 2; ++i) {
            const int o = wid * 2 + i;   // 0..7
            const int c = o >> 1;
            const int rh = o & 1;
            const uint8_t* ga = xe + (size_t)(bm + rh * 64 + lane) * KB_TOT + kt * 64 + c * 16;
            gload_lds16(ga, &As[c][rh * 64][0]);
            const uint8_t* gb = we + (size_t)(bn + rh * 64 + lane) * KB_TOT + kt * 64 + c * 16;
            gload_lds16(gb, &Bs[c][rh * 64][0]);
        }
        // ---- stage scales: threads 0..127 -> Sa, 128..255 -> Sb ----
        {
            const int which = tid >> 7;
            const int tt = tid & 127;
            const int blk = tt >> 5;   // 0..3
            const int d = tt & 31;     // dword within 128 rows
            if (which == 0) {
                unsigned v = *(const unsigned*)(sxT + (size_t)(kt * 4 + blk) * M_DIM + bm + d * 4);
                *(unsigned*)&Sa[blk][d * 4] = v;
            } else {
                unsigned v = *(const unsigned*)(swT + (size_t)(kt * 4 + blk) * N_DIM + bn + d * 4);
                *(unsigned*)&Sb[blk][d * 4] = v;
            }
        }
        __syncthreads();

        // ---- compute: 2 K-sub-steps of 64, 2x2 fragments of 32x32 ----
        const int h = lane >> 5;
        const int r = lane & 31;
#pragma unroll
        for (int kk = 0; kk < 2; ++kk) {
            const int c = kk * 2 + h;
            i32x4 af[2], bf[2];
            int sa[2], sb[2];
#pragma unroll
            for (int mi = 0; mi < 2; ++mi) {
                const int row = wr * 64 + mi * 32 + r;
                af[mi] = *(const i32x4*)&As[c][row][0];
                sa[mi] = Sa[c][row];
            }
#pragma unroll
            for (int ni = 0; ni < 2; ++ni) {
                const int row = wc * 64 + ni * 32 + r;
                bf[ni] = *(const i32x4*)&Bs[c][row][0];
                sb[ni] = Sb[c][row];
            }
#pragma unroll
            for (int mi = 0; mi < 2; ++mi)
#pragma unroll
                for (int ni = 0; ni < 2; ++ni) {
                    i32x8 a8 = {af[mi].x, af[mi].y, af[mi].z, af[mi].w, 0, 0, 0, 0};
                    i32x8 b8 = {bf[ni].x, bf[ni].y, bf[ni].z, bf[ni].w, 0, 0, 0, 0};
                    acc[mi][ni] = __builtin_amdgcn_mfma_scale_f32_32x32x64_f8f6f4(
                        a8, b8, acc[mi][ni], 4, 4, 0, sa[mi], 0, sb[ni]);
                }
        }
    }

    // ---- epilogue: 32x32 C/D layout col=lane&31, row=(reg&3)+8*(reg>>2)+4*(lane>>5) ----
#pragma unroll
    for (int mi = 0; mi < 2; ++mi)
#pragma unroll
        for (int ni = 0; ni < 2; ++ni) {
            const int col = bn + wc * 64 + ni * 32 + (lane & 31);
            const int rb = bm + wr * 64 + mi * 32 + 4 * (lane >> 5);
#pragma unroll
            for (int reg = 0; reg < 16; ++reg) {
                const int row = rb + (reg & 3) + 8 * (reg >> 2);
                out[(size_t)row * N_DIM + col] = acc[mi][ni][reg];
            }
        }
}

// ======================= R1 fallback (fused f16 dequant GEMM) =======================
__device__ inline short8 dequant8_f16(i32x4 q, int sf) {
    unsigned b = (unsigned)q.x | ((unsigned)q.y << 8) |
                 ((unsigned)q.z << 16) | ((unsigned)q.w << 24);
    unsigned me = b & 0x07070707u;
    unsigned mo = (b >> 4) & 0x07070707u;
    const unsigned TLO = 0x3E3C3800u;
    const unsigned THI = 0x46444240u;
    unsigned He = __builtin_amdgcn_perm(THI, TLO, me);
    unsigned Ho = __builtin_amdgcn_perm(THI, TLO, mo);
    He |= (b & 0x08080808u) << 4;
    Ho |= (b & 0x80808080u);
    unsigned d0 = __builtin_amdgcn_perm(He, 0u, 0x05010400u);
    unsigned d1 = __builtin_amdgcn_perm(He, 0u, 0x07000600u);
    unsigned d2 = __builtin_amdgcn_perm(Ho, 0u, 0x05010400u);
    unsigned d3 = __builtin_amdgcn_perm(Ho, 0u, 0x07000600u);
    i32x4 di; di.x = (int)d0; di.y = (int)d1; di.z = (int)d2; di.w = (int)d3;
    half8 hh = __builtin_bit_cast(half8, di);
    unsigned short se = (unsigned short)((sf - 112) << 10);
    int srep = (int)((unsigned)se | ((unsigned)se << 16));
    i32x4 si; si.x = srep; si.y = srep; si.z = srep; si.w = srep;
    hh = hh * __builtin_bit_cast(half8, si);
    return __builtin_bit_cast(short8, hh);
}

__global__ __launch_bounds__(256)
void l4b_fused(const int* __restrict__ x_q, const int* __restrict__ scales_x,
               const int* __restrict__ weight, const int* __restrict__ SF_w,
               const int* __restrict__ lrw, const int* __restrict__ SF_lr,
               float* __restrict__ out) {
    __shared__ short As[128 * 64];
    __shared__ short Bs[128 * 64];
    const int tid = threadIdx.x;
    const int lane = tid & 63;
    const int wid = tid >> 6;
    const int wr = wid >> 1, wc = wid & 1;
    const int bm = blockIdx.y * 128, bn = blockIdx.x * 128;
    const int srow = tid >> 3;
    const int scol = (tid & 7) * 8;
    f32x4 acc[4][4] = {};
    for (int kt = 0; kt < K_TOT / 64; ++kt) {
        const int k0 = kt * 64;
        __syncthreads();
#pragma unroll
        for (int it = 0; it < 4; ++it) {
            const int row = it * 32 + srow;
            const int k = k0 + scol;
            const int ksrc = (k < K_MAIN) ? k : (k - K_MAIN);
            i32x4 q = *(const i32x4*)(x_q + (size_t)(bm + row) * 2048 + (ksrc >> 1));
            int sf = scales_x[(size_t)(bm + row) * 128 + (ksrc >> 5)];
            short8 v = dequant8_f16(q, sf);
            unsigned a = (unsigned)(row * 128 + scol * 2) ^ (unsigned)((row & 7) << 4);
            *(short8*)((char*)As + a) = v;
        }
#pragma unroll
        for (int it = 0; it < 4; ++it) {
            const int row = it * 32 + srow;
            const int k = k0 + scol;
            i32x4 q; int sf;
            if (k < K_MAIN) {
                q = *(const i32x4*)(weight + (size_t)(bn + row) * 2048 + (k >> 1));
                sf = SF_w[(size_t)(bn + row) * 128 + (k >> 5)];
            } else {
                q = *(const i32x4*)(lrw + (size_t)(bn + row) * 64 + ((k - K_MAIN) >> 1));
                sf = SF_lr[(size_t)(bn + row) * 4 + ((k - K_MAIN) >> 5)];
            }
            short8 v = dequant8_f16(q, sf);
            unsigned a = (unsigned)(row * 128 + scol * 2) ^ (unsigned)((row & 7) << 4);
            *(short8*)((char*)Bs + a) = v;
        }
        __syncthreads();
#pragma unroll
        for (int ks = 0; ks < 2; ++ks) {
            const int koff = ks * 32 + (lane >> 4) * 8;
            short8 af[4], bfr[4];
#pragma unroll
            for (int mi = 0; mi < 4; ++mi) {
                const int row = wr * 64 + mi * 16 + (lane & 15);
                unsigned a = (unsigned)(row * 128 + koff * 2) ^ (unsigned)((row & 7) << 4);
                af[mi] = *(const short8*)((const char*)As + a);
            }
#pragma unroll
            for (int ni = 0; ni < 4; ++ni) {
                const int row = wc * 64 + ni * 16 + (lane & 15);
                unsigned a = (unsigned)(row * 128 + koff * 2) ^ (unsigned)((row & 7) << 4);
                bfr[ni] = *(const short8*)((const char*)Bs + a);
            }
#pragma unroll
            for (int mi = 0; mi < 4; ++mi)
#pragma unroll
                for (int ni = 0; ni < 4; ++ni)
                    acc[mi][ni] = __builtin_amdgcn_mfma_f32_16x16x32_f16(
                        __builtin_bit_cast(half8, af[mi]),
                        __builtin_bit_cast(half8, bfr[ni]),
                        acc[mi][ni], 0, 0, 0);
        }
    }
#pragma unroll
    for (int mi = 0; mi < 4; ++mi)
#pragma unroll
        for (int ni = 0; ni < 4; ++ni) {
            const int col = bn + wc * 64 + ni * 16 + (lane & 15);
            const int row0 = bm + wr * 64 + mi * 16 + (lane >> 4) * 4;
#pragma unroll
            for (int r2 = 0; r2 < 4; ++r2)
                out[(size_t)(row0 + r2) * N_DIM + col] = acc[mi][ni][r2];
        }
}

extern "C" void kernel_launch(void* const* d_in, const int* in_sizes, int n_in,
                              void* d_out, int out_size, void* d_ws, size_t ws_size,
                              hipStream_t stream) {
    const int* x_q  = (const int*)d_in[0];
    const int* sx   = (const int*)d_in[1];
    const int* w    = (const int*)d_in[2];
    const int* sfw  = (const int*)d_in[3];
    const int* lrw  = (const int*)d_in[4];
    const int* sflr = (const int*)d_in[5];
    float* out = (float*)d_out;

    if (ws_size >= WS_NEED) {
        uint8_t* ws = (uint8_t*)d_ws;
        pack_kernel<<<PACK_TOTAL / 256, 256, 0, stream>>>(x_q, sx, w, sfw, lrw, sflr, ws);
        l4b_mx<<<(M_DIM / 128) * (N_DIM / 128), 256, 0, stream>>>(
            ws + XE_OFF, ws + WE_OFF, ws + SXT_OFF, ws + SWT_OFF, out);
    } else {
        dim3 grid(N_DIM / 128, M_DIM / 128);
        l4b_fused<<<grid, dim3(256), 0, stream>>>(x_q, sx, w, sfw, lrw, sflr, out);
    }
}

// Round 3
// 139.282 us; speedup vs baseline: 3.7394x; 1.0966x over previous
//
#include <hip/hip_runtime.h>
#include <hip/hip_bf16.h>
#include <stdint.h>

// Linear4bit R3: pack pre-pass (int32-bytes -> packed fp4 + interleaved scale
// planes) + MX-fp4 GEMM, 256x256 tile, 8 waves (2x4), 4x2 frags of 32x32x64,
// depth-2 LDS double-buffer with prefetch, setprio around MFMA.

#define M_DIM 8192
#define N_DIM 4096
#define K_MAIN 4096
#define K_TOT 4224
#define KB_TOT 2112   // packed bytes per extended row
#define NT 33         // K-tiles of 128 elements

// ---- ws layout ----
#define XE_OFF   ((size_t)0)
#define WE_OFF   (XE_OFF + (size_t)M_DIM * KB_TOT)     // 17,301,504
#define SXH_OFF  (WE_OFF + (size_t)N_DIM * KB_TOT)     // 25,952,256
#define SWH_OFF  (SXH_OFF + (size_t)NT * 2 * M_DIM * 2) // +1,081,344 = 27,033,600
#define WS_NEED  (SWH_OFF + (size_t)NT * 2 * N_DIM * 2) // +540,672  = 27,574,272

typedef __attribute__((ext_vector_type(4))) float f32x4;
typedef __attribute__((ext_vector_type(16))) float f32x16;
typedef __attribute__((ext_vector_type(8))) short short8;
typedef __attribute__((ext_vector_type(8))) _Float16 half8;
typedef __attribute__((ext_vector_type(4))) int i32x4;
typedef __attribute__((ext_vector_type(8))) int i32x8;

// ======================= pack / transpose pre-pass =======================
#define PX_N  (M_DIM * (KB_TOT / 4))            // 4,325,376
#define PW_N  (N_DIM * (KB_TOT / 4))            // 2,162,688
#define TSX_N (NT * 2 * M_DIM / 2)              // 270,336 dwords
#define TSW_N (NT * 2 * N_DIM / 2)              // 135,168 dwords
#define PACK_TOTAL (PX_N + PW_N + TSX_N + TSW_N)

__global__ __launch_bounds__(256)
void pack_kernel(const int* __restrict__ xq, const int* __restrict__ sx,
                 const int* __restrict__ w, const int* __restrict__ sfw,
                 const int* __restrict__ lrw, const int* __restrict__ sflr,
                 uint8_t* __restrict__ ws) {
    int t = blockIdx.x * 256 + threadIdx.x;
    if (t < PX_N) {
        int row = t / (KB_TOT / 4);
        int j = (t % (KB_TOT / 4)) * 4;
        int jsrc = (j < 2048) ? j : (j - 2048);  // low-rank replays x[:, :128]
        i32x4 q = *(const i32x4*)(xq + (size_t)row * 2048 + jsrc);
        unsigned v = (q.x & 255) | ((q.y & 255) << 8) | ((q.z & 255) << 16) |
                     ((unsigned)(q.w & 255) << 24);
        *(unsigned*)(ws + XE_OFF + (size_t)row * KB_TOT + j) = v;
    } else if (t < PX_N + PW_N) {
        int i = t - PX_N;
        int row = i / (KB_TOT / 4);
        int j = (i % (KB_TOT / 4)) * 4;
        i32x4 q;
        if (j < 2048) q = *(const i32x4*)(w + (size_t)row * 2048 + j);
        else          q = *(const i32x4*)(lrw + (size_t)row * 64 + (j - 2048));
        unsigned v = (q.x & 255) | ((q.y & 255) << 8) | ((q.z & 255) << 16) |
                     ((unsigned)(q.w & 255) << 24);
        *(unsigned*)(ws + WE_OFF + (size_t)row * KB_TOT + j) = v;
    } else if (t < PX_N + PW_N + TSX_N) {
        // sxH[kt][h][row] ushort = scale bytes for k-chunks (kt*4+h, kt*4+2+h)
        int i = t - PX_N - PW_N;
        int plane = i >> 12;            // kt*2 + h, 0..65
        int kt = plane >> 1, h = plane & 1;
        int r2 = (i & 4095) << 1;       // even row
        int g0 = kt * 4 + h, g2 = g0 + 2;
        int s0 = (g0 < 128) ? g0 : g0 - 128;
        int s2 = (g2 < 128) ? g2 : g2 - 128;
        unsigned b0 = sx[(size_t)r2 * 128 + s0] & 255;
        unsigned b1 = sx[(size_t)r2 * 128 + s2] & 255;
        unsigned b2 = sx[(size_t)(r2 + 1) * 128 + s0] & 255;
        unsigned b3 = sx[(size_t)(r2 + 1) * 128 + s2] & 255;
        *(unsigned*)(ws + SXH_OFF + (size_t)i * 4) = b0 | (b1 << 8) | (b2 << 16) | (b3 << 24);
    } else if (t < PACK_TOTAL) {
        int i = t - PX_N - PW_N - TSX_N;
        int plane = i >> 11;            // 0..65
        int kt = plane >> 1, h = plane & 1;
        int r2 = (i & 2047) << 1;
        int g0 = kt * 4 + h, g2 = g0 + 2;
        unsigned b0, b1, b2, b3;
        if (g0 < 128) { b0 = sfw[(size_t)r2 * 128 + g0] & 255; b2 = sfw[(size_t)(r2 + 1) * 128 + g0] & 255; }
        else          { b0 = sflr[(size_t)r2 * 4 + (g0 - 128)] & 255; b2 = sflr[(size_t)(r2 + 1) * 4 + (g0 - 128)] & 255; }
        if (g2 < 128) { b1 = sfw[(size_t)r2 * 128 + g2] & 255; b3 = sfw[(size_t)(r2 + 1) * 128 + g2] & 255; }
        else          { b1 = sflr[(size_t)r2 * 4 + (g2 - 128)] & 255; b3 = sflr[(size_t)(r2 + 1) * 4 + (g2 - 128)] & 255; }
        *(unsigned*)(ws + SWH_OFF + (size_t)i * 4) = b0 | (b1 << 8) | (b2 << 16) | (b3 << 24);
    }
}

// ======================= MX-fp4 GEMM =======================
__device__ inline void gload_lds16(const void* g, void* l) {
    __builtin_amdgcn_global_load_lds(
        (const __attribute__((address_space(1))) unsigned int*)g,
        (__attribute__((address_space(3))) unsigned int*)l, 16, 0, 0);
}

// LDS tile: [chunk c=0..3][row 0..255][16B]; chunk c = k-bytes [c*16, c*16+16)
__device__ inline void stage_tile(const uint8_t* __restrict__ xe,
                                  const uint8_t* __restrict__ we,
                                  int bm, int bn, int tt,
                                  uint8_t (*As)[256][16], uint8_t (*Bs)[256][16],
                                  int wid, int lane) {
    if (wid < 4) {
        const int c = wid;
        const uint8_t* g = xe + (size_t)(bm + lane) * KB_TOT + tt * 64 + c * 16;
#pragma unroll
        for (int q = 0; q < 4; ++q)
            gload_lds16(g + (size_t)q * 64 * KB_TOT, &As[c][q * 64][0]);
    } else {
        const int c = wid - 4;
        const uint8_t* g = we + (size_t)(bn + lane) * KB_TOT + tt * 64 + c * 16;
#pragma unroll
        for (int q = 0; q < 4; ++q)
            gload_lds16(g + (size_t)q * 64 * KB_TOT, &Bs[c][q * 64][0]);
    }
}

__device__ inline void load_scales(const uint8_t* __restrict__ sxH,
                                   const uint8_t* __restrict__ swH,
                                   int bm, int bn, int tt, int* sa, int* sb,
                                   int wr, int wc, int lane) {
    const int h = lane >> 5, r = lane & 31;
    const uint8_t* px = sxH + (size_t)((tt * 2 + h) * M_DIM + bm + wr * 128 + r) * 2;
#pragma unroll
    for (int mi = 0; mi < 4; ++mi) sa[mi] = *(const unsigned short*)(px + mi * 64);
    const uint8_t* pw = swH + (size_t)((tt * 2 + h) * N_DIM + bn + wc * 64 + r) * 2;
#pragma unroll
    for (int ni = 0; ni < 2; ++ni) sb[ni] = *(const unsigned short*)(pw + ni * 64);
}

template <int KK>
__device__ inline void compute_phase(const uint8_t (*As)[256][16],
                                     const uint8_t (*Bs)[256][16],
                                     f32x16 (&acc)[4][2], const int* sa, const int* sb,
                                     int wr, int wc, int lane) {
    const int h = lane >> 5, r = lane & 31;
    const int c = KK * 2 + h;
    i32x4 af[4], bf[2];
#pragma unroll
    for (int mi = 0; mi < 4; ++mi)
        af[mi] = *(const i32x4*)&As[c][wr * 128 + mi * 32 + r][0];
#pragma unroll
    for (int ni = 0; ni < 2; ++ni)
        bf[ni] = *(const i32x4*)&Bs[c][wc * 64 + ni * 32 + r][0];
    __builtin_amdgcn_s_setprio(1);
#pragma unroll
    for (int mi = 0; mi < 4; ++mi)
#pragma unroll
        for (int ni = 0; ni < 2; ++ni) {
            i32x8 a8 = {af[mi].x, af[mi].y, af[mi].z, af[mi].w, 0, 0, 0, 0};
            i32x8 b8 = {bf[ni].x, bf[ni].y, bf[ni].z, bf[ni].w, 0, 0, 0, 0};
            acc[mi][ni] = __builtin_amdgcn_mfma_scale_f32_32x32x64_f8f6f4(
                a8, b8, acc[mi][ni], 4, 4, KK, sa[mi], KK, sb[ni]);
        }
    __builtin_amdgcn_s_setprio(0);
}

__global__ __launch_bounds__(512, 2)
void l4b_mx2(const uint8_t* __restrict__ xe, const uint8_t* __restrict__ we,
             const uint8_t* __restrict__ sxH, const uint8_t* __restrict__ swH,
             float* __restrict__ out) {
    __shared__ __align__(16) uint8_t As[2][4][256][16];
    __shared__ __align__(16) uint8_t Bs[2][4][256][16];

    const int tid = threadIdx.x;
    const int lane = tid & 63;
    const int wid = tid >> 6;
    const int wr = wid >> 2;   // 0..1
    const int wc = wid & 3;    // 0..3

    // XCD-aware bijective swizzle: 512 blocks = 8 XCDs x 64
    const int bid = blockIdx.x;
    const int wgid = (bid & 7) * 64 + (bid >> 3);
    const int bm = (wgid & 31) * 256;   // M/256 = 32
    const int bn = (wgid >> 5) * 256;   // N/256 = 16 (W-panel resident per XCD)

    f32x16 acc[4][2] = {};
    int sa[4], sb[2], san[4], sbn[2];

    stage_tile(xe, we, bm, bn, 0, As[0], Bs[0], wid, lane);
    load_scales(sxH, swH, bm, bn, 0, sa, sb, wr, wc, lane);
    __syncthreads();  // drains vmcnt+lgkmcnt, then barrier

    int cur = 0;
    for (int t = 0; t < NT - 1; ++t) {
        const int nxt = cur ^ 1;
        // prefetch next tile (data -> LDS[nxt], scales -> regs)
        stage_tile(xe, we, bm, bn, t + 1, As[nxt], Bs[nxt], wid, lane);
        load_scales(sxH, swH, bm, bn, t + 1, san, sbn, wr, wc, lane);
        // compute current tile (2 K-sub-phases of 64)
        compute_phase<0>(As[cur], Bs[cur], acc, sa, sb, wr, wc, lane);
        compute_phase<1>(As[cur], Bs[cur], acc, sa, sb, wr, wc, lane);
        __syncthreads();  // drain prefetch + protect LDS reuse
        cur = nxt;
#pragma unroll
        for (int i = 0; i < 4; ++i) sa[i] = san[i];
        sb[0] = sbn[0]; sb[1] = sbn[1];
    }
    compute_phase<0>(As[cur], Bs[cur], acc, sa, sb, wr, wc, lane);
    compute_phase<1>(As[cur], Bs[cur], acc, sa, sb, wr, wc, lane);

    // epilogue: 32x32 C/D layout col=lane&31, row=(reg&3)+8*(reg>>2)+4*(lane>>5)
#pragma unroll
    for (int mi = 0; mi < 4; ++mi)
#pragma unroll
        for (int ni = 0; ni < 2; ++ni) {
            const int col = bn + wc * 64 + ni * 32 + (lane & 31);
            const int rb = bm + wr * 128 + mi * 32 + 4 * (lane >> 5);
#pragma unroll
            for (int reg = 0; reg < 16; ++reg) {
                const int row = rb + (reg & 3) + 8 * (reg >> 2);
                out[(size_t)row * N_DIM + col] = acc[mi][ni][reg];
            }
        }
}

// ======================= fallback (fused f16 dequant GEMM) =======================
__device__ inline short8 dequant8_f16(i32x4 q, int sf) {
    unsigned b = (unsigned)q.x | ((unsigned)q.y << 8) |
                 ((unsigned)q.z << 16) | ((unsigned)q.w << 24);
    unsigned me = b & 0x07070707u;
    unsigned mo = (b >> 4) & 0x07070707u;
    const unsigned TLO = 0x3E3C3800u;
    const unsigned THI = 0x46444240u;
    unsigned He = __builtin_amdgcn_perm(THI, TLO, me);
    unsigned Ho = __builtin_amdgcn_perm(THI, TLO, mo);
    He |= (b & 0x08080808u) << 4;
    Ho |= (b & 0x80808080u);
    unsigned d0 = __builtin_amdgcn_perm(He, 0u, 0x05010400u);
    unsigned d1 = __builtin_amdgcn_perm(He, 0u, 0x07000600u);
    unsigned d2 = __builtin_amdgcn_perm(Ho, 0u, 0x05010400u);
    unsigned d3 = __builtin_amdgcn_perm(Ho, 0u, 0x07000600u);
    i32x4 di; di.x = (int)d0; di.y = (int)d1; di.z = (int)d2; di.w = (int)d3;
    half8 hh = __builtin_bit_cast(half8, di);
    unsigned short se = (unsigned short)((sf - 112) << 10);
    int srep = (int)((unsigned)se | ((unsigned)se << 16));
    i32x4 si; si.x = srep; si.y = srep; si.z = srep; si.w = srep;
    hh = hh * __builtin_bit_cast(half8, si);
    return __builtin_bit_cast(short8, hh);
}

__global__ __launch_bounds__(256)
void l4b_fused(const int* __restrict__ x_q, const int* __restrict__ scales_x,
               const int* __restrict__ weight, const int* __restrict__ SF_w,
               const int* __restrict__ lrw, const int* __restrict__ SF_lr,
               float* __restrict__ out) {
    __shared__ short As[128 * 64];
    __shared__ short Bs[128 * 64];
    const int tid = threadIdx.x;
    const int lane = tid & 63;
    const int wid = tid >> 6;
    const int wr = wid >> 1, wc = wid & 1;
    const int bm = blockIdx.y * 128, bn = blockIdx.x * 128;
    const int srow = tid >> 3;
    const int scol = (tid & 7) * 8;
    f32x4 acc[4][4] = {};
    for (int kt = 0; kt < K_TOT / 64; ++kt) {
        const int k0 = kt * 64;
        __syncthreads();
#pragma unroll
        for (int it = 0; it < 4; ++it) {
            const int row = it * 32 + srow;
            const int k = k0 + scol;
            const int ksrc = (k < K_MAIN) ? k : (k - K_MAIN);
            i32x4 q = *(const i32x4*)(x_q + (size_t)(bm + row) * 2048 + (ksrc >> 1));
            int sf = scales_x[(size_t)(bm + row) * 128 + (ksrc >> 5)];
            short8 v = dequant8_f16(q, sf);
            unsigned a = (unsigned)(row * 128 + scol * 2) ^ (unsigned)((row & 7) << 4);
            *(short8*)((char*)As + a) = v;
        }
#pragma unroll
        for (int it = 0; it < 4; ++it) {
            const int row = it * 32 + srow;
            const int k = k0 + scol;
            i32x4 q; int sf;
            if (k < K_MAIN) {
                q = *(const i32x4*)(weight + (size_t)(bn + row) * 2048 + (k >> 1));
                sf = SF_w[(size_t)(bn + row) * 128 + (k >> 5)];
            } else {
                q = *(const i32x4*)(lrw + (size_t)(bn + row) * 64 + ((k - K_MAIN) >> 1));
                sf = SF_lr[(size_t)(bn + row) * 4 + ((k - K_MAIN) >> 5)];
            }
            short8 v = dequant8_f16(q, sf);
            unsigned a = (unsigned)(row * 128 + scol * 2) ^ (unsigned)((row & 7) << 4);
            *(short8*)((char*)Bs + a) = v;
        }
        __syncthreads();
#pragma unroll
        for (int ks = 0; ks < 2; ++ks) {
            const int koff = ks * 32 + (lane >> 4) * 8;
            short8 af[4], bfr[4];
#pragma unroll
            for (int mi = 0; mi < 4; ++mi) {
                const int row = wr * 64 + mi * 16 + (lane & 15);
                unsigned a = (unsigned)(row * 128 + koff * 2) ^ (unsigned)((row & 7) << 4);
                af[mi] = *(const short8*)((const char*)As + a);
            }
#pragma unroll
            for (int ni = 0; ni < 4; ++ni) {
                const int row = wc * 64 + ni * 16 + (lane & 15);
                unsigned a = (unsigned)(row * 128 + koff * 2) ^ (unsigned)((row & 7) << 4);
                bfr[ni] = *(const short8*)((const char*)Bs + a);
            }
#pragma unroll
            for (int mi = 0; mi < 4; ++mi)
#pragma unroll
                for (int ni = 0; ni < 4; ++ni)
                    acc[mi][ni] = __builtin_amdgcn_mfma_f32_16x16x32_f16(
                        __builtin_bit_cast(half8, af[mi]),
                        __builtin_bit_cast(half8, bfr[ni]),
                        acc[mi][ni], 0, 0, 0);
        }
    }
#pragma unroll
    for (int mi = 0; mi < 4; ++mi)
#pragma unroll
        for (int ni = 0; ni < 4; ++ni) {
            const int col = bn + wc * 64 + ni * 16 + (lane & 15);
            const int row0 = bm + wr * 64 + mi * 16 + (lane >> 4) * 4;
#pragma unroll
            for (int r2 = 0; r2 < 4; ++r2)
                out[(size_t)(row0 + r2) * N_DIM + col] = acc[mi][ni][r2];
        }
}

extern "C" void kernel_launch(void* const* d_in, const int* in_sizes, int n_in,
                              void* d_out, int out_size, void* d_ws, size_t ws_size,
                              hipStream_t stream) {
    const int* x_q  = (const int*)d_in[0];
    const int* sx   = (const int*)d_in[1];
    const int* w    = (const int*)d_in[2];
    const int* sfw  = (const int*)d_in[3];
    const int* lrw  = (const int*)d_in[4];
    const int* sflr = (const int*)d_in[5];
    float* out = (float*)d_out;

    if (ws_size >= WS_NEED) {
        uint8_t* ws = (uint8_t*)d_ws;
        pack_kernel<<<(PACK_TOTAL + 255) / 256, 256, 0, stream>>>(x_q, sx, w, sfw, lrw, sflr, ws);
        l4b_mx2<<<(M_DIM / 256) * (N_DIM / 256), 512, 0, stream>>>(
            ws + XE_OFF, ws + WE_OFF, ws + SXH_OFF, ws + SWH_OFF, out);
    } else {
        dim3 grid(N_DIM / 128, M_DIM / 128);
        l4b_fused<<<grid, dim3(256), 0, stream>>>(x_q, sx, w, sfw, lrw, sflr, out);
    }
}

// Round 4
// 119.087 us; speedup vs baseline: 4.3735x; 1.1696x over previous
//
#include <hip/hip_runtime.h>
#include <hip/hip_bf16.h>
#include <stdint.h>

// Linear4bit R4: pack pre-pass now emits CHUNK-MAJOR packed fp4
// (xp[g][m][16B], one 16B chunk = one 32-elem MX block) so GEMM staging is
// lane-contiguous (1KB/wave-op). GEMM: 256x256 tile, 8 waves, 4x2 frags of
// 32x32x64 mfma_scale, depth-2 LDS dbuf, setprio. K extended to 4224 (LR fold).

#define M_DIM 8192
#define N_DIM 4096
#define K_MAIN 4096
#define K_TOT 4224
#define NCHUNK 132    // 16B chunks per extended row
#define NT 33         // K-tiles of 128 elements

// ---- ws layout ----
#define XP_OFF   ((size_t)0)
#define WP_OFF   (XP_OFF + (size_t)NCHUNK * M_DIM * 16)   // 17,301,504
#define SXH_OFF  (WP_OFF + (size_t)NCHUNK * N_DIM * 16)   // 25,952,256
#define SWH_OFF  (SXH_OFF + (size_t)NT * 2 * M_DIM * 2)   // 27,033,600
#define WS_NEED  (SWH_OFF + (size_t)NT * 2 * N_DIM * 2)   // 27,574,272

typedef __attribute__((ext_vector_type(4))) float f32x4;
typedef __attribute__((ext_vector_type(16))) float f32x16;
typedef __attribute__((ext_vector_type(8))) short short8;
typedef __attribute__((ext_vector_type(8))) _Float16 half8;
typedef __attribute__((ext_vector_type(4))) int i32x4;
typedef __attribute__((ext_vector_type(8))) int i32x8;

// ======================= pack / transpose pre-pass =======================
#define PXP_N (NCHUNK * M_DIM)      // 1,081,344 threads, 16B out each
#define PWP_N (NCHUNK * N_DIM)      //   540,672
#define TSX_N (NT * 2 * M_DIM / 2)  //   270,336 (dwords)
#define TSW_N (NT * 2 * N_DIM / 2)  //   135,168
#define PACK_TOTAL (PXP_N + PWP_N + TSX_N + TSW_N)

__device__ inline unsigned pack4(i32x4 q) {
    return (q.x & 255) | ((q.y & 255) << 8) | ((q.z & 255) << 16) |
           ((unsigned)(q.w & 255) << 24);
}

__global__ __launch_bounds__(256)
void pack_kernel(const int* __restrict__ xq, const int* __restrict__ sx,
                 const int* __restrict__ w, const int* __restrict__ sfw,
                 const int* __restrict__ lrw, const int* __restrict__ sflr,
                 uint8_t* __restrict__ ws) {
    int t = blockIdx.x * 256 + threadIdx.x;
    if (t < PXP_N) {
        // xp[g][m][16B]: bytes g*16..g*16+15 of extended row m (g>=128 replays 0..63)
        const int g = t >> 13;          // /8192
        const int m = t & 8191;
        const int gs = (g < 128) ? g : (g - 128);
        const int* src = xq + (size_t)m * 2048 + gs * 16;
        i32x4 o;
        o.x = (int)pack4(*(const i32x4*)(src + 0));
        o.y = (int)pack4(*(const i32x4*)(src + 4));
        o.z = (int)pack4(*(const i32x4*)(src + 8));
        o.w = (int)pack4(*(const i32x4*)(src + 12));
        *(i32x4*)(ws + XP_OFF + ((size_t)g * M_DIM + m) * 16) = o;
    } else if (t < PXP_N + PWP_N) {
        const int i = t - PXP_N;
        const int g = i >> 12;          // /4096
        const int n = i & 4095;
        const int* src = (g < 128) ? (w + (size_t)n * 2048 + g * 16)
                                   : (lrw + (size_t)n * 64 + (g - 128) * 16);
        i32x4 o;
        o.x = (int)pack4(*(const i32x4*)(src + 0));
        o.y = (int)pack4(*(const i32x4*)(src + 4));
        o.z = (int)pack4(*(const i32x4*)(src + 8));
        o.w = (int)pack4(*(const i32x4*)(src + 12));
        *(i32x4*)(ws + WP_OFF + ((size_t)g * N_DIM + n) * 16) = o;
    } else if (t < PXP_N + PWP_N + TSX_N) {
        // sxH[kt][h][row] ushort = scale bytes for k-chunks (kt*4+h, kt*4+2+h)
        int i = t - PXP_N - PWP_N;
        int plane = i >> 12;            // kt*2 + h, 0..65
        int kt = plane >> 1, h = plane & 1;
        int r2 = (i & 4095) << 1;       // even row
        int g0 = kt * 4 + h, g2 = g0 + 2;
        int s0 = (g0 < 128) ? g0 : g0 - 128;
        int s2 = (g2 < 128) ? g2 : g2 - 128;
        unsigned b0 = sx[(size_t)r2 * 128 + s0] & 255;
        unsigned b1 = sx[(size_t)r2 * 128 + s2] & 255;
        unsigned b2 = sx[(size_t)(r2 + 1) * 128 + s0] & 255;
        unsigned b3 = sx[(size_t)(r2 + 1) * 128 + s2] & 255;
        *(unsigned*)(ws + SXH_OFF + (size_t)i * 4) = b0 | (b1 << 8) | (b2 << 16) | (b3 << 24);
    } else if (t < PACK_TOTAL) {
        int i = t - PXP_N - PWP_N - TSX_N;
        int plane = i >> 11;            // 0..65
        int kt = plane >> 1, h = plane & 1;
        int r2 = (i & 2047) << 1;
        int g0 = kt * 4 + h, g2 = g0 + 2;
        unsigned b0, b1, b2, b3;
        if (g0 < 128) { b0 = sfw[(size_t)r2 * 128 + g0] & 255; b2 = sfw[(size_t)(r2 + 1) * 128 + g0] & 255; }
        else          { b0 = sflr[(size_t)r2 * 4 + (g0 - 128)] & 255; b2 = sflr[(size_t)(r2 + 1) * 4 + (g0 - 128)] & 255; }
        if (g2 < 128) { b1 = sfw[(size_t)r2 * 128 + g2] & 255; b3 = sfw[(size_t)(r2 + 1) * 128 + g2] & 255; }
        else          { b1 = sflr[(size_t)r2 * 4 + (g2 - 128)] & 255; b3 = sflr[(size_t)(r2 + 1) * 4 + (g2 - 128)] & 255; }
        *(unsigned*)(ws + SWH_OFF + (size_t)i * 4) = b0 | (b1 << 8) | (b2 << 16) | (b3 << 24);
    }
}

// ======================= MX-fp4 GEMM =======================
__device__ inline void gload_lds16(const void* g, void* l) {
    __builtin_amdgcn_global_load_lds(
        (const __attribute__((address_space(1))) unsigned int*)g,
        (__attribute__((address_space(3))) unsigned int*)l, 16, 0, 0);
}

// LDS tile: [chunk c=0..3][row 0..255][16B]. Staging: wave wid<4 -> A chunk
// wid, wid>=4 -> B chunk wid-4; per wave 4x 1KB contiguous gload_lds.
__device__ inline void stage_tile(const uint8_t* __restrict__ xp,
                                  const uint8_t* __restrict__ wp,
                                  int bm, int bn, int tt,
                                  uint8_t (*As)[256][16], uint8_t (*Bs)[256][16],
                                  int wid, int lane) {
    const int c = wid & 3;
    if (wid < 4) {
        const uint8_t* g = xp + ((size_t)(tt * 4 + c) * M_DIM + bm + lane) * 16;
#pragma unroll
        for (int q = 0; q < 4; ++q)
            gload_lds16(g + (size_t)q * 64 * 16, &As[c][q * 64][0]);
    } else {
        const uint8_t* g = wp + ((size_t)(tt * 4 + c) * N_DIM + bn + lane) * 16;
#pragma unroll
        for (int q = 0; q < 4; ++q)
            gload_lds16(g + (size_t)q * 64 * 16, &Bs[c][q * 64][0]);
    }
}

__device__ inline void load_scales(const uint8_t* __restrict__ sxH,
                                   const uint8_t* __restrict__ swH,
                                   int bm, int bn, int tt, int* sa, int* sb,
                                   int wr, int wc, int lane) {
    const int h = lane >> 5, r = lane & 31;
    const uint8_t* px = sxH + (size_t)((tt * 2 + h) * M_DIM + bm + wr * 128 + r) * 2;
#pragma unroll
    for (int mi = 0; mi < 4; ++mi) sa[mi] = *(const unsigned short*)(px + mi * 64);
    const uint8_t* pw = swH + (size_t)((tt * 2 + h) * N_DIM + bn + wc * 64 + r) * 2;
#pragma unroll
    for (int ni = 0; ni < 2; ++ni) sb[ni] = *(const unsigned short*)(pw + ni * 64);
}

template <int KK>
__device__ inline void compute_phase(const uint8_t (*As)[256][16],
                                     const uint8_t (*Bs)[256][16],
                                     f32x16 (&acc)[4][2], const int* sa, const int* sb,
                                     int wr, int wc, int lane) {
    const int h = lane >> 5, r = lane & 31;
    const int c = KK * 2 + h;
    i32x4 af[4], bf[2];
#pragma unroll
    for (int mi = 0; mi < 4; ++mi)
        af[mi] = *(const i32x4*)&As[c][wr * 128 + mi * 32 + r][0];
#pragma unroll
    for (int ni = 0; ni < 2; ++ni)
        bf[ni] = *(const i32x4*)&Bs[c][wc * 64 + ni * 32 + r][0];
    __builtin_amdgcn_s_setprio(1);
#pragma unroll
    for (int mi = 0; mi < 4; ++mi)
#pragma unroll
        for (int ni = 0; ni < 2; ++ni) {
            i32x8 a8 = {af[mi].x, af[mi].y, af[mi].z, af[mi].w, 0, 0, 0, 0};
            i32x8 b8 = {bf[ni].x, bf[ni].y, bf[ni].z, bf[ni].w, 0, 0, 0, 0};
            acc[mi][ni] = __builtin_amdgcn_mfma_scale_f32_32x32x64_f8f6f4(
                a8, b8, acc[mi][ni], 4, 4, KK, sa[mi], KK, sb[ni]);
        }
    __builtin_amdgcn_s_setprio(0);
}

__global__ __launch_bounds__(512, 2)
void l4b_mx3(const uint8_t* __restrict__ xp, const uint8_t* __restrict__ wp,
             const uint8_t* __restrict__ sxH, const uint8_t* __restrict__ swH,
             float* __restrict__ out) {
    __shared__ __align__(16) uint8_t As[2][4][256][16];
    __shared__ __align__(16) uint8_t Bs[2][4][256][16];

    const int tid = threadIdx.x;
    const int lane = tid & 63;
    const int wid = tid >> 6;
    const int wr = wid >> 2;   // 0..1
    const int wc = wid & 3;    // 0..3

    // XCD-aware bijective swizzle: 512 blocks = 8 XCDs x 64
    const int bid = blockIdx.x;
    const int wgid = (bid & 7) * 64 + (bid >> 3);
    const int bm = (wgid & 31) * 256;   // M/256 = 32
    const int bn = (wgid >> 5) * 256;   // N/256 = 16

    f32x16 acc[4][2] = {};
    int sa[4], sb[2], san[4], sbn[2];

    stage_tile(xp, wp, bm, bn, 0, As[0], Bs[0], wid, lane);
    load_scales(sxH, swH, bm, bn, 0, sa, sb, wr, wc, lane);
    __syncthreads();

    int cur = 0;
    for (int t = 0; t < NT - 1; ++t) {
        const int nxt = cur ^ 1;
        stage_tile(xp, wp, bm, bn, t + 1, As[nxt], Bs[nxt], wid, lane);
        load_scales(sxH, swH, bm, bn, t + 1, san, sbn, wr, wc, lane);
        compute_phase<0>(As[cur], Bs[cur], acc, sa, sb, wr, wc, lane);
        compute_phase<1>(As[cur], Bs[cur], acc, sa, sb, wr, wc, lane);
        __syncthreads();
        cur = nxt;
#pragma unroll
        for (int i = 0; i < 4; ++i) sa[i] = san[i];
        sb[0] = sbn[0]; sb[1] = sbn[1];
    }
    compute_phase<0>(As[cur], Bs[cur], acc, sa, sb, wr, wc, lane);
    compute_phase<1>(As[cur], Bs[cur], acc, sa, sb, wr, wc, lane);

    // epilogue: 32x32 C/D layout col=lane&31, row=(reg&3)+8*(reg>>2)+4*(lane>>5)
#pragma unroll
    for (int mi = 0; mi < 4; ++mi)
#pragma unroll
        for (int ni = 0; ni < 2; ++ni) {
            const int col = bn + wc * 64 + ni * 32 + (lane & 31);
            const int rb = bm + wr * 128 + mi * 32 + 4 * (lane >> 5);
#pragma unroll
            for (int reg = 0; reg < 16; ++reg) {
                const int row = rb + (reg & 3) + 8 * (reg >> 2);
                out[(size_t)row * N_DIM + col] = acc[mi][ni][reg];
            }
        }
}

// ======================= fallback (fused f16 dequant GEMM) =======================
__device__ inline short8 dequant8_f16(i32x4 q, int sf) {
    unsigned b = (unsigned)q.x | ((unsigned)q.y << 8) |
                 ((unsigned)q.z << 16) | ((unsigned)q.w << 24);
    unsigned me = b & 0x07070707u;
    unsigned mo = (b >> 4) & 0x07070707u;
    const unsigned TLO = 0x3E3C3800u;
    const unsigned THI = 0x46444240u;
    unsigned He = __builtin_amdgcn_perm(THI, TLO, me);
    unsigned Ho = __builtin_amdgcn_perm(THI, TLO, mo);
    He |= (b & 0x08080808u) << 4;
    Ho |= (b & 0x80808080u);
    unsigned d0 = __builtin_amdgcn_perm(He, 0u, 0x05010400u);
    unsigned d1 = __builtin_amdgcn_perm(He, 0u, 0x07000600u);
    unsigned d2 = __builtin_amdgcn_perm(Ho, 0u, 0x05010400u);
    unsigned d3 = __builtin_amdgcn_perm(Ho, 0u, 0x07000600u);
    i32x4 di; di.x = (int)d0; di.y = (int)d1; di.z = (int)d2; di.w = (int)d3;
    half8 hh = __builtin_bit_cast(half8, di);
    unsigned short se = (unsigned short)((sf - 112) << 10);
    int srep = (int)((unsigned)se | ((unsigned)se << 16));
    i32x4 si; si.x = srep; si.y = srep; si.z = srep; si.w = srep;
    hh = hh * __builtin_bit_cast(half8, si);
    return __builtin_bit_cast(short8, hh);
}

__global__ __launch_bounds__(256)
void l4b_fused(const int* __restrict__ x_q, const int* __restrict__ scales_x,
               const int* __restrict__ weight, const int* __restrict__ SF_w,
               const int* __restrict__ lrw, const int* __restrict__ SF_lr,
               float* __restrict__ out) {
    __shared__ short As[128 * 64];
    __shared__ short Bs[128 * 64];
    const int tid = threadIdx.x;
    const int lane = tid & 63;
    const int wid = tid >> 6;
    const int wr = wid >> 1, wc = wid & 1;
    const int bm = blockIdx.y * 128, bn = blockIdx.x * 128;
    const int srow = tid >> 3;
    const int scol = (tid & 7) * 8;
    f32x4 acc[4][4] = {};
    for (int kt = 0; kt < K_TOT / 64; ++kt) {
        const int k0 = kt * 64;
        __syncthreads();
#pragma unroll
        for (int it = 0; it < 4; ++it) {
            const int row = it * 32 + srow;
            const int k = k0 + scol;
            const int ksrc = (k < K_MAIN) ? k : (k - K_MAIN);
            i32x4 q = *(const i32x4*)(x_q + (size_t)(bm + row) * 2048 + (ksrc >> 1));
            int sf = scales_x[(size_t)(bm + row) * 128 + (ksrc >> 5)];
            short8 v = dequant8_f16(q, sf);
            unsigned a = (unsigned)(row * 128 + scol * 2) ^ (unsigned)((row & 7) << 4);
            *(short8*)((char*)As + a) = v;
        }
#pragma unroll
        for (int it = 0; it < 4; ++it) {
            const int row = it * 32 + srow;
            const int k = k0 + scol;
            i32x4 q; int sf;
            if (k < K_MAIN) {
                q = *(const i32x4*)(weight + (size_t)(bn + row) * 2048 + (k >> 1));
                sf = SF_w[(size_t)(bn + row) * 128 + (k >> 5)];
            } else {
                q = *(const i32x4*)(lrw + (size_t)(bn + row) * 64 + ((k - K_MAIN) >> 1));
                sf = SF_lr[(size_t)(bn + row) * 4 + ((k - K_MAIN) >> 5)];
            }
            short8 v = dequant8_f16(q, sf);
            unsigned a = (unsigned)(row * 128 + scol * 2) ^ (unsigned)((row & 7) << 4);
            *(short8*)((char*)Bs + a) = v;
        }
        __syncthreads();
#pragma unroll
        for (int ks = 0; ks < 2; ++ks) {
            const int koff = ks * 32 + (lane >> 4) * 8;
            short8 af[4], bfr[4];
#pragma unroll
            for (int mi = 0; mi < 4; ++mi) {
                const int row = wr * 64 + mi * 16 + (lane & 15);
                unsigned a = (unsigned)(row * 128 + koff * 2) ^ (unsigned)((row & 7) << 4);
                af[mi] = *(const short8*)((const char*)As + a);
            }
#pragma unroll
            for (int ni = 0; ni < 4; ++ni) {
                const int row = wc * 64 + ni * 16 + (lane & 15);
                unsigned a = (unsigned)(row * 128 + koff * 2) ^ (unsigned)((row & 7) << 4);
                bfr[ni] = *(const short8*)((const char*)Bs + a);
            }
#pragma unroll
            for (int mi = 0; mi < 4; ++mi)
#pragma unroll
                for (int ni = 0; ni < 4; ++ni)
                    acc[mi][ni] = __builtin_amdgcn_mfma_f32_16x16x32_f16(
                        __builtin_bit_cast(half8, af[mi]),
                        __builtin_bit_cast(half8, bfr[ni]),
                        acc[mi][ni], 0, 0, 0);
        }
    }
#pragma unroll
    for (int mi = 0; mi < 4; ++mi)
#pragma unroll
        for (int ni = 0; ni < 4; ++ni) {
            const int col = bn + wc * 64 + ni * 16 + (lane & 15);
            const int row0 = bm + wr * 64 + mi * 16 + (lane >> 4) * 4;
#pragma unroll
            for (int r2 = 0; r2 < 4; ++r2)
                out[(size_t)(row0 + r2) * N_DIM + col] = acc[mi][ni][r2];
        }
}

extern "C" void kernel_launch(void* const* d_in, const int* in_sizes, int n_in,
                              void* d_out, int out_size, void* d_ws, size_t ws_size,
                              hipStream_t stream) {
    const int* x_q  = (const int*)d_in[0];
    const int* sx   = (const int*)d_in[1];
    const int* w    = (const int*)d_in[2];
    const int* sfw  = (const int*)d_in[3];
    const int* lrw  = (const int*)d_in[4];
    const int* sflr = (const int*)d_in[5];
    float* out = (float*)d_out;

    if (ws_size >= WS_NEED) {
        uint8_t* ws = (uint8_t*)d_ws;
        pack_kernel<<<(PACK_TOTAL + 255) / 256, 256, 0, stream>>>(x_q, sx, w, sfw, lrw, sflr, ws);
        l4b_mx3<<<(M_DIM / 256) * (N_DIM / 256), 512, 0, stream>>>(
            ws + XP_OFF, ws + WP_OFF, ws + SXH_OFF, ws + SWH_OFF, out);
    } else {
        dim3 grid(N_DIM / 128, M_DIM / 128);
        l4b_fused<<<grid, dim3(256), 0, stream>>>(x_q, sx, w, sfw, lrw, sflr, out);
    }
}